// Round 5
// baseline (1921.335 us; speedup 1.0000x reference)
//
#include <hip/hip_runtime.h>

// Billeh column GLIF forward — one fused kernel per timestep, block-bucketed
// edge layout, LDS accumulation.
//
// Round-4 post-mortem: (a) per-post CSR fill had 7.9x write amplification
// (113us); (b) per-thread variable-length row gather was imbalance/serial
// bound (23us/step vs round-0's 18us for scatter+update). This version keeps
// 1 dispatch/step but processes edges scatter-style: edges are bucketed by
// destination block (512 post-neurons); each block walks its contiguous edge
// range with a flat coalesced strided loop, gates on an LDS-staged 12.5KB
// spike bitmask, and accumulates into a 2048-float LDS accumulator via LDS
// atomics (only ~4% of edges pass the gate). Kernel boundary = global sync.

constexpr int RR = 4;
constexpr int BS = 512;                 // neurons per block = bucket size

// ---------------- setup: state init + param packing ----------------
__global__ void init_state_kernel(const float* __restrict__ v0,
                                  const float* __restrict__ v_th,
                                  const float* __restrict__ v_rst,
                                  const float* __restrict__ t_rf,
                                  const float* __restrict__ decay,
                                  const float* __restrict__ curf,
                                  const float* __restrict__ e_l,
                                  const float2* __restrict__ aamps,
                                  const float2* __restrict__ adec,
                                  float4* __restrict__ psc,
                                  float4* __restrict__ psc_rise,
                                  float* __restrict__ v, float* __restrict__ r,
                                  float2* __restrict__ asc,
                                  float4* __restrict__ p0, float4* __restrict__ p1,
                                  float2* __restrict__ p2,
                                  unsigned long long* __restrict__ maskA,
                                  unsigned long long* __restrict__ maskB,
                                  int* __restrict__ bcount,
                                  int N, int nmask, int NBK) {
    int i = blockIdx.x * blockDim.x + threadIdx.x;
    if (i < N) {
        psc[i] = make_float4(0.f, 0.f, 0.f, 0.f);
        psc_rise[i] = make_float4(0.f, 0.f, 0.f, 0.f);
        v[i] = v0[i]; r[i] = 0.f;
        asc[i] = make_float2(0.f, 0.f);
        p0[i] = make_float4(v_th[i], v_rst[i], t_rf[i], decay[i]);
        float2 aa = aamps[i];
        p1[i] = make_float4(curf[i], e_l[i], aa.x, aa.y);
        p2[i] = adec[i];
    }
    if (i < nmask) { maskA[i] = 0ull; maskB[i] = 0ull; }
    if (i <= NBK) bcount[i] = 0;
}

// ---------------- bucket build (bucket = post >> 9) ----------------
__global__ void count_kernel(const int* __restrict__ post, int* __restrict__ bcount,
                             int E, int NBK) {
    __shared__ int h[1024];
    for (int i = threadIdx.x; i < NBK; i += blockDim.x) h[i] = 0;
    __syncthreads();
    int stride = gridDim.x * blockDim.x;
    for (int e = blockIdx.x * blockDim.x + threadIdx.x; e < E; e += stride)
        atomicAdd(&h[post[e] >> 9], 1);
    __syncthreads();
    for (int i = threadIdx.x; i < NBK; i += blockDim.x)
        if (h[i]) atomicAdd(&bcount[i], h[i]);
}

// single-block exclusive scan of bucket counts -> bstart, bcursor
__global__ void scan_kernel(const int* __restrict__ bcount,
                            int* __restrict__ bstart, int* __restrict__ bcursor,
                            int NBK, int E) {
    __shared__ int s[1024];
    if (NBK > 1024) {
        if (threadIdx.x == 0) {
            int acc = 0;
            for (int b = 0; b < NBK; b++) { bstart[b] = acc; bcursor[b] = acc; acc += bcount[b]; }
            bstart[NBK] = E;
        }
        return;
    }
    int tid = threadIdx.x;
    int vv = (tid < NBK) ? bcount[tid] : 0;
    s[tid] = vv;
    __syncthreads();
    for (int off = 1; off < 1024; off <<= 1) {
        int t = (tid >= off) ? s[tid - off] : 0;
        __syncthreads();
        s[tid] += t;
        __syncthreads();
    }
    if (tid < NBK) { int st = s[tid] - vv; bstart[tid] = st; bcursor[tid] = st; }
    if (tid == 0) bstart[NBK] = E;
}

// edge record: { pre(18b) | rc<<18 | local_idx<<20 , w }
__global__ void fill_kernel(const int* __restrict__ pre, const int* __restrict__ post,
                            const int* __restrict__ rc, const float* __restrict__ w,
                            int* __restrict__ bcursor, uint2* __restrict__ ebuf, int E) {
    int stride = gridDim.x * blockDim.x;
    for (int e = blockIdx.x * blockDim.x + threadIdx.x; e < E; e += stride) {
        int pn = post[e];
        unsigned packed = (unsigned)pre[e] | ((unsigned)rc[e] << 18)
                        | ((unsigned)(pn & (BS - 1)) << 20);
        int k = atomicAdd(&bcursor[pn >> 9], 1);
        ebuf[k] = make_uint2(packed, __float_as_uint(w[e]));
    }
}

// ---------------- per-step fused edge-scatter + neuron update ----------------
__global__ void __launch_bounds__(BS)
step_kernel(const float4* __restrict__ x_t,
            const uint2* __restrict__ ebuf,
            const int* __restrict__ bstart,
            const unsigned long long* __restrict__ mask_in,
            unsigned long long* __restrict__ mask_out,
            float4* __restrict__ psc,
            float4* __restrict__ psc_rise,
            float* __restrict__ v, float* __restrict__ r,
            float2* __restrict__ asc,
            const float4* __restrict__ p0,   // vth, vrst, tref, decay
            const float4* __restrict__ p1,   // curf, e_l, aa0, aa1
            const float2* __restrict__ p2,   // ad0, ad1
            const float* __restrict__ syn_d4,
            const float* __restrict__ psc_i4,
            float* __restrict__ out_t,
            int N, int nmask)
{
    extern __shared__ unsigned long long sdyn[];
    unsigned long long* smask = sdyn;                   // nmask u64
    float* sacc = (float*)(sdyn + nmask);               // BS*4 floats
    const int tid = threadIdx.x;
    const int n = blockIdx.x * BS + tid;
    const bool own = n < N;

    // stage prev-step spike bitmask into LDS + zero accumulators
    bool any = false;
    for (int i = tid; i < nmask; i += BS) {
        unsigned long long m = mask_in[i];
        smask[i] = m;
        any |= (m != 0ull);
    }
#pragma unroll
    for (int j = 0; j < RR; j++) sacc[tid + j * BS] = 0.f;
    // issue x_t load early; consumed after the edge loop
    float4 xt = own ? x_t[n] : make_float4(0.f, 0.f, 0.f, 0.f);
    const int anyspk = __syncthreads_or(any ? 1 : 0);   // barrier + block-OR

    // ---- flat, balanced, coalesced walk of this block's edge bucket ----
    if (anyspk) {
        const int s = bstart[blockIdx.x], e = bstart[blockIdx.x + 1];
        for (int j = s + tid; j < e; j += BS) {
            uint2 ed = ebuf[j];
            unsigned p = ed.x & 0x3FFFFu;
            if ((smask[p >> 6] >> (p & 63)) & 1ull)
                atomicAdd(&sacc[ed.x >> 18], __uint_as_float(ed.y));  // lidx*4+rc
        }
    }
    __syncthreads();

    // ---- dense neuron update ----
    float nz = 0.f;
    if (own) {
        const float sd0 = syn_d4[0], sd1 = syn_d4[1], sd2 = syn_d4[2], sd3 = syn_d4[3];
        const float pi0 = psc_i4[0], pi1 = psc_i4[1], pi2 = psc_i4[2], pi3 = psc_i4[3];

        float zz = (float)((smask[n >> 6] >> (n & 63)) & 1ull);   // prev spike
        float acc0 = sacc[tid * 4 + 0], acc1 = sacc[tid * 4 + 1];
        float acc2 = sacc[tid * 4 + 2], acc3 = sacc[tid * 4 + 3];

        float4 pr = psc_rise[n];
        float4 pc = psc[n];
        float i0 = acc0 + xt.x, i1 = acc1 + xt.y, i2 = acc2 + xt.z, i3 = acc3 + xt.w;
        float npr0 = pr.x * sd0 + i0 * pi0;
        float npr1 = pr.y * sd1 + i1 * pi1;
        float npr2 = pr.z * sd2 + i2 * pi2;
        float npr3 = pr.w * sd3 + i3 * pi3;
        float npc0 = pc.x * sd0 + sd0 * pr.x;    // OLD psc_rise, DT=1
        float npc1 = pc.y * sd1 + sd1 * pr.y;
        float npc2 = pc.z * sd2 + sd2 * pr.z;
        float npc3 = pc.w * sd3 + sd3 * pr.w;
        float in_cur = npc0 + npc1 + npc2 + npc3;
        psc_rise[n] = make_float4(npr0, npr1, npr2, npr3);
        psc[n]      = make_float4(npc0, npc1, npc2, npc3);

        float2 a  = asc[n];
        float asum = a.x + a.y;                  // OLD asc sum
        float4 P0 = p0[n];                       // vth, vrst, tref, decay
        float4 P1 = p1[n];                       // curf, e_l, aa0, aa1
        float2 ad = p2[n];
        asc[n] = make_float2(ad.x * a.x + zz * P1.z, ad.y * a.y + zz * P1.w);

        float vth = P0.x;
        float vv  = P0.w * v[n] + P1.x * (in_cur + asum + P1.y) + zz * (P0.y - vth);
        float vsc = (vv - vth) / vth;
        float rn  = r[n];
        nz = (vsc > 0.f) ? 1.f : 0.f;
        if (rn > 0.f) nz = 0.f;                  // refractory mask (OLD r)
        float nr  = fmaxf(rn - 1.f + nz * P0.z, 0.f);

        v[n] = vv;
        r[n] = nr;
        out_t[n] = nz;
    }

    // publish this step's spike bitmask (one store per wave, no atomics)
    unsigned long long bal = __ballot(nz > 0.f);
    if (own && (tid & 63) == 0) mask_out[n >> 6] = bal;
}

// ---------------- launch ----------------
extern "C" void kernel_launch(void* const* d_in, const int* in_sizes, int n_in,
                              void* d_out, int out_size, void* d_ws, size_t ws_size,
                              hipStream_t stream) {
    const float* w_rec = (const float*)d_in[0];
    const float* x_ext = (const float*)d_in[1];
    const float* v0    = (const float*)d_in[2];
    const float* v_th  = (const float*)d_in[3];
    const float* v_rst = (const float*)d_in[4];
    const float* t_rf  = (const float*)d_in[5];
    const float* decay = (const float*)d_in[6];
    const float* curf  = (const float*)d_in[7];
    const float* e_l   = (const float*)d_in[8];
    const float* aamps = (const float*)d_in[9];
    const float* adec  = (const float*)d_in[10];
    const float* syn_d = (const float*)d_in[11];
    const float* psc_i = (const float*)d_in[12];
    const int*   pre   = (const int*)d_in[13];
    const int*   post  = (const int*)d_in[14];
    const int*   rc    = (const int*)d_in[15];

    const int E = in_sizes[0];
    const int N = in_sizes[2];            // B == 1
    const int T = in_sizes[1] / (N * RR);
    const int nmask = (N + 63) / 64;
    const int NBK = (N + BS - 1) / BS;    // buckets == step blocks

    // -------- workspace layout --------
    char* ws = (char*)d_ws;
    float4* psc      = (float4*)ws;                       ws += (size_t)N * 16;
    float4* psc_rise = (float4*)ws;                       ws += (size_t)N * 16;
    float4* p0       = (float4*)ws;                       ws += (size_t)N * 16;
    float4* p1       = (float4*)ws;                       ws += (size_t)N * 16;
    float2* p2       = (float2*)ws;                       ws += (size_t)N * 8;
    float2* asc      = (float2*)ws;                       ws += (size_t)N * 8;
    float*  v        = (float*)ws;                        ws += (size_t)N * 4;
    float*  r        = (float*)ws;                        ws += (size_t)N * 4;
    uint2*  ebuf     = (uint2*)ws;                        ws += (size_t)E * 8;
    unsigned long long* maskA = (unsigned long long*)ws;  ws += (size_t)nmask * 8;
    unsigned long long* maskB = (unsigned long long*)ws;  ws += (size_t)nmask * 8;
    int* bstart      = (int*)ws;                          ws += (size_t)(NBK + 1) * 4;
    int* bcount      = (int*)ws;                          ws += (size_t)(NBK + 1) * 4;
    int* bcursor     = (int*)ws;                          /* +(NBK+1)*4 */

    // -------- one-time setup (4 dispatches) --------
    init_state_kernel<<<(N + 255) / 256, 256, 0, stream>>>(
        v0, v_th, v_rst, t_rf, decay, curf, e_l,
        (const float2*)aamps, (const float2*)adec,
        psc, psc_rise, v, r, asc, p0, p1, p2, maskA, maskB, bcount, N, nmask, NBK);
    count_kernel<<<256, 256, 0, stream>>>(post, bcount, E, NBK);
    scan_kernel<<<1, 1024, 0, stream>>>(bcount, bstart, bcursor, NBK, E);
    fill_kernel<<<2048, 256, 0, stream>>>(pre, post, rc, w_rec, bcursor, ebuf, E);

    // -------- T fused steps; double-buffered spike bitmask --------
    const size_t smbytes = (size_t)nmask * 8 + (size_t)BS * RR * 4;  // ~20.5 KB
    for (int t = 0; t < T; ++t) {
        const unsigned long long* min_ = (t & 1) ? maskB : maskA;
        unsigned long long* mout = (t & 1) ? maskA : maskB;
        step_kernel<<<NBK, BS, smbytes, stream>>>(
            (const float4*)(x_ext + (size_t)t * N * RR),
            ebuf, bstart, min_, mout,
            psc, psc_rise, v, r, asc, p0, p1, p2,
            syn_d, psc_i, (float*)d_out + (size_t)t * N, N, nmask);
    }
}

// Round 6
// 942.514 us; speedup vs baseline: 2.0385x; 2.0385x over previous
//
#include <hip/hip_runtime.h>

// Billeh column GLIF forward — one fused kernel per timestep, block-bucketed
// edge layout (LDS accumulation), contention-free radix-partition edge build.
//
// Round-5 post-mortem: step structure is good (~14.6us/step) but the bucket
// fill funneled 2M global atomics through 196 cursors -> 1115us of RMW
// serialization. This version builds the same bucketed layout with a
// deterministic 3-pass partition: per-chunk LDS histogram (no atomics),
// single-block exclusive scan of the bucket-major histogram, then fill with
// per-block LDS cursors (contention block-local only). Step kernel unchanged
// structurally, with state packed as {v,r,asc0,asc1} and vrst-vth prefolded.

constexpr int RR  = 4;
constexpr int BS  = 512;                // neurons per block = bucket size
constexpr int NCH = 256;                // partition chunks

// ---------------- setup: state init + param packing ----------------
__global__ void init_state_kernel(const float* __restrict__ v0,
                                  const float* __restrict__ v_th,
                                  const float* __restrict__ v_rst,
                                  const float* __restrict__ t_rf,
                                  const float* __restrict__ decay,
                                  const float* __restrict__ curf,
                                  const float* __restrict__ e_l,
                                  const float2* __restrict__ aamps,
                                  const float2* __restrict__ adec,
                                  float4* __restrict__ psc,
                                  float4* __restrict__ psc_rise,
                                  float4* __restrict__ st,     // v, r, asc0, asc1
                                  float4* __restrict__ p0, float4* __restrict__ p1,
                                  float2* __restrict__ p2,
                                  unsigned long long* __restrict__ maskA,
                                  unsigned long long* __restrict__ maskB,
                                  int N, int nmask) {
    int i = blockIdx.x * blockDim.x + threadIdx.x;
    if (i < N) {
        psc[i] = make_float4(0.f, 0.f, 0.f, 0.f);
        psc_rise[i] = make_float4(0.f, 0.f, 0.f, 0.f);
        st[i] = make_float4(v0[i], 0.f, 0.f, 0.f);
        float vth = v_th[i];
        p0[i] = make_float4(vth, v_rst[i] - vth, t_rf[i], decay[i]);
        float2 aa = aamps[i];
        p1[i] = make_float4(curf[i], e_l[i], aa.x, aa.y);
        p2[i] = adec[i];
    }
    if (i < nmask) { maskA[i] = 0ull; maskB[i] = 0ull; }
}

// ---------------- pass 1: per-chunk bucket histogram (no atomics) ----------
__global__ void count_kernel(const int* __restrict__ post, int* __restrict__ ghist,
                             int E, int CH, int NBK) {
    __shared__ int h[1024];
    for (int i = threadIdx.x; i < NBK; i += blockDim.x) h[i] = 0;
    __syncthreads();
    const int b = blockIdx.x;
    const int lo = b * CH, hi = min(lo + CH, E);
    for (int e = lo + threadIdx.x; e < hi; e += blockDim.x)
        atomicAdd(&h[post[e] >> 9], 1);          // LDS atomic: block-local
    __syncthreads();
    for (int i = threadIdx.x; i < NBK; i += blockDim.x)
        ghist[i * NCH + b] = h[i];               // bucket-major store
}

// ---------------- pass 2: exclusive scan of ghist (one block) --------------
__global__ void scan_kernel(int* __restrict__ ghist, int* __restrict__ bstart,
                            int NBK, int E) {
    __shared__ int s[1024];
    const int M = NBK * NCH;
    const int seg = (M + 1023) / 1024;
    const int tid = threadIdx.x;
    const int base = tid * seg;
    const int lim = min(base + seg, M);
    int sum = 0;
    for (int i = base; i < lim; ++i) sum += ghist[i];
    s[tid] = sum;
    __syncthreads();
    for (int off = 1; off < 1024; off <<= 1) {
        int t = (tid >= off) ? s[tid - off] : 0;
        __syncthreads();
        s[tid] += t;
        __syncthreads();
    }
    int run = s[tid] - sum;                      // exclusive prefix
    for (int i = base; i < lim; ++i) { int t = ghist[i]; ghist[i] = run; run += t; }
    __syncthreads();
    if (tid < NBK) bstart[tid] = ghist[tid * NCH];
    if (tid == 0)  bstart[NBK] = E;
}

// ---------------- pass 3: fill with block-local LDS cursors ----------------
// edge record: { pre(18b) | rc<<18 | local_idx<<20 , w }
__global__ void fill_kernel(const int* __restrict__ pre, const int* __restrict__ post,
                            const int* __restrict__ rc, const float* __restrict__ w,
                            const int* __restrict__ ghist,
                            uint2* __restrict__ ebuf, int E, int CH, int NBK) {
    __shared__ int cur[1024];
    const int b = blockIdx.x;
    for (int i = threadIdx.x; i < NBK; i += blockDim.x)
        cur[i] = ghist[i * NCH + b];
    __syncthreads();
    const int lo = b * CH, hi = min(lo + CH, E);
    for (int e = lo + threadIdx.x; e < hi; e += blockDim.x) {
        int pn = post[e];
        int k = atomicAdd(&cur[pn >> 9], 1);     // LDS atomic: block-local
        unsigned packed = (unsigned)pre[e] | ((unsigned)rc[e] << 18)
                        | ((unsigned)(pn & (BS - 1)) << 20);
        ebuf[k] = make_uint2(packed, __float_as_uint(w[e]));
    }
}

// ---------------- per-step fused edge-scatter + neuron update --------------
__global__ void __launch_bounds__(BS)
step_kernel(const float4* __restrict__ x_t,
            const uint2* __restrict__ ebuf,
            const int* __restrict__ bstart,
            const unsigned long long* __restrict__ mask_in,
            unsigned long long* __restrict__ mask_out,
            float4* __restrict__ psc,
            float4* __restrict__ psc_rise,
            float4* __restrict__ st,         // v, r, asc0, asc1
            const float4* __restrict__ p0,   // vth, vrst-vth, tref, decay
            const float4* __restrict__ p1,   // curf, e_l, aa0, aa1
            const float2* __restrict__ p2,   // ad0, ad1
            const float* __restrict__ syn_d4,
            const float* __restrict__ psc_i4,
            float* __restrict__ out_t,
            int N, int nmask)
{
    extern __shared__ unsigned long long sdyn[];
    unsigned long long* smask = sdyn;                   // nmask u64
    float* sacc = (float*)(sdyn + nmask);               // BS*4 floats
    const int tid = threadIdx.x;
    const int n = blockIdx.x * BS + tid;
    const bool own = n < N;

    // stage prev-step spike bitmask into LDS + zero accumulators
    bool any = false;
    for (int i = tid; i < nmask; i += BS) {
        unsigned long long m = mask_in[i];
        smask[i] = m;
        any |= (m != 0ull);
    }
#pragma unroll
    for (int j = 0; j < RR; j++) sacc[tid + j * BS] = 0.f;
    // issue x_t load early; consumed after the edge loop
    float4 xt = own ? x_t[n] : make_float4(0.f, 0.f, 0.f, 0.f);
    const int anyspk = __syncthreads_or(any ? 1 : 0);   // barrier + block-OR

    // ---- flat, balanced, coalesced walk of this block's edge bucket ----
    if (anyspk) {
        const int s = bstart[blockIdx.x], e = bstart[blockIdx.x + 1];
        for (int j = s + tid; j < e; j += BS) {
            uint2 ed = ebuf[j];
            unsigned p = ed.x & 0x3FFFFu;
            if ((smask[p >> 6] >> (p & 63)) & 1ull)
                atomicAdd(&sacc[ed.x >> 18], __uint_as_float(ed.y));  // lidx*4+rc
        }
    }
    __syncthreads();

    // ---- dense neuron update ----
    float nz = 0.f;
    if (own) {
        const float sd0 = syn_d4[0], sd1 = syn_d4[1], sd2 = syn_d4[2], sd3 = syn_d4[3];
        const float pi0 = psc_i4[0], pi1 = psc_i4[1], pi2 = psc_i4[2], pi3 = psc_i4[3];

        float zz = (float)((smask[n >> 6] >> (n & 63)) & 1ull);   // prev spike
        float acc0 = sacc[tid * 4 + 0], acc1 = sacc[tid * 4 + 1];
        float acc2 = sacc[tid * 4 + 2], acc3 = sacc[tid * 4 + 3];

        float4 pr = psc_rise[n];
        float4 pc = psc[n];
        float4 S  = st[n];                       // v, r, asc0, asc1
        float4 P0 = p0[n];                       // vth, vrst-vth, tref, decay
        float4 P1 = p1[n];                       // curf, e_l, aa0, aa1
        float2 ad = p2[n];

        float i0 = acc0 + xt.x, i1 = acc1 + xt.y, i2 = acc2 + xt.z, i3 = acc3 + xt.w;
        float npr0 = pr.x * sd0 + i0 * pi0;
        float npr1 = pr.y * sd1 + i1 * pi1;
        float npr2 = pr.z * sd2 + i2 * pi2;
        float npr3 = pr.w * sd3 + i3 * pi3;
        float npc0 = pc.x * sd0 + sd0 * pr.x;    // OLD psc_rise, DT=1
        float npc1 = pc.y * sd1 + sd1 * pr.y;
        float npc2 = pc.z * sd2 + sd2 * pr.z;
        float npc3 = pc.w * sd3 + sd3 * pr.w;
        float in_cur = npc0 + npc1 + npc2 + npc3;
        psc_rise[n] = make_float4(npr0, npr1, npr2, npr3);
        psc[n]      = make_float4(npc0, npc1, npc2, npc3);

        float asum = S.z + S.w;                  // OLD asc sum
        float na0 = ad.x * S.z + zz * P1.z;
        float na1 = ad.y * S.w + zz * P1.w;

        float vth = P0.x;
        float vv  = P0.w * S.x + P1.x * (in_cur + asum + P1.y) + zz * P0.y;
        float rn  = S.y;
        nz = (vv > vth) ? 1.f : 0.f;             // (vv-vth)/vth > 0, vth > 0
        if (rn > 0.f) nz = 0.f;                  // refractory mask (OLD r)
        float nr  = fmaxf(rn - 1.f + nz * P0.z, 0.f);

        st[n] = make_float4(vv, nr, na0, na1);
        out_t[n] = nz;
    }

    // publish this step's spike bitmask (one store per wave, no atomics)
    unsigned long long bal = __ballot(nz > 0.f);
    if (own && (tid & 63) == 0) mask_out[n >> 6] = bal;
}

// ---------------- launch ----------------
extern "C" void kernel_launch(void* const* d_in, const int* in_sizes, int n_in,
                              void* d_out, int out_size, void* d_ws, size_t ws_size,
                              hipStream_t stream) {
    const float* w_rec = (const float*)d_in[0];
    const float* x_ext = (const float*)d_in[1];
    const float* v0    = (const float*)d_in[2];
    const float* v_th  = (const float*)d_in[3];
    const float* v_rst = (const float*)d_in[4];
    const float* t_rf  = (const float*)d_in[5];
    const float* decay = (const float*)d_in[6];
    const float* curf  = (const float*)d_in[7];
    const float* e_l   = (const float*)d_in[8];
    const float* aamps = (const float*)d_in[9];
    const float* adec  = (const float*)d_in[10];
    const float* syn_d = (const float*)d_in[11];
    const float* psc_i = (const float*)d_in[12];
    const int*   pre   = (const int*)d_in[13];
    const int*   post  = (const int*)d_in[14];
    const int*   rc    = (const int*)d_in[15];

    const int E = in_sizes[0];
    const int N = in_sizes[2];            // B == 1
    const int T = in_sizes[1] / (N * RR);
    const int nmask = (N + 63) / 64;
    const int NBK = (N + BS - 1) / BS;    // buckets == step blocks
    const int CH  = (E + NCH - 1) / NCH;  // edges per partition chunk

    // -------- workspace layout --------
    char* ws = (char*)d_ws;
    float4* psc      = (float4*)ws;                       ws += (size_t)N * 16;
    float4* psc_rise = (float4*)ws;                       ws += (size_t)N * 16;
    float4* st       = (float4*)ws;                       ws += (size_t)N * 16;
    float4* p0       = (float4*)ws;                       ws += (size_t)N * 16;
    float4* p1       = (float4*)ws;                       ws += (size_t)N * 16;
    float2* p2       = (float2*)ws;                       ws += (size_t)N * 8;
    uint2*  ebuf     = (uint2*)ws;                        ws += (size_t)E * 8;
    unsigned long long* maskA = (unsigned long long*)ws;  ws += (size_t)nmask * 8;
    unsigned long long* maskB = (unsigned long long*)ws;  ws += (size_t)nmask * 8;
    int* ghist       = (int*)ws;                          ws += (size_t)NBK * NCH * 4;
    int* bstart      = (int*)ws;                          /* +(NBK+1)*4 */

    // -------- one-time setup (4 dispatches, contention-free) --------
    init_state_kernel<<<(N + 255) / 256, 256, 0, stream>>>(
        v0, v_th, v_rst, t_rf, decay, curf, e_l,
        (const float2*)aamps, (const float2*)adec,
        psc, psc_rise, st, p0, p1, p2, maskA, maskB, N, nmask);
    count_kernel<<<NCH, 256, 0, stream>>>(post, ghist, E, CH, NBK);
    scan_kernel<<<1, 1024, 0, stream>>>(ghist, bstart, NBK, E);
    fill_kernel<<<NCH, 256, 0, stream>>>(pre, post, rc, w_rec, ghist, ebuf, E, CH, NBK);

    // -------- T fused steps; double-buffered spike bitmask --------
    const size_t smbytes = (size_t)nmask * 8 + (size_t)BS * RR * 4;  // ~20.7 KB
    for (int t = 0; t < T; ++t) {
        const unsigned long long* min_ = (t & 1) ? maskB : maskA;
        unsigned long long* mout = (t & 1) ? maskA : maskB;
        step_kernel<<<NBK, BS, smbytes, stream>>>(
            (const float4*)(x_ext + (size_t)t * N * RR),
            ebuf, bstart, min_, mout,
            psc, psc_rise, st, p0, p1, p2,
            syn_d, psc_i, (float*)d_out + (size_t)t * N, N, nmask);
    }
}

// Round 7
// 708.130 us; speedup vs baseline: 2.7133x; 1.3310x over previous
//
#include <hip/hip_runtime.h>

// Billeh column GLIF forward — persistent step loop over block-bucketed edges.
//
// Design from measured evidence (R0-R6):
//  - Bucketed edge layout + LDS accumulation is the best step structure
//    (R6: ~14.6us/step measured, no global atomics in the hot loop).
//  - Neuron state lives in REGISTERS across all T steps (block owns its 512
//    neurons; nothing but the 12.5KB spike mask crosses blocks).
//  - Grid sync: per-step 64B-padded arrival counter + last-arriver release
//    word; relaxed scoped atomics ONLY (R1 lesson: agent fences = full-L2
//    wb/inv storms; R2 lesson: no per-thread MALL ops per step; R3 lesson:
//    no acquire fence, no master-poll chain, ONE barrier/step).
//  - Mask double-buffered by step parity so one barrier/step suffices.
//  - Setup scan rebuilt hierarchical+coalesced (R6: 78us -> ~6us).

constexpr int RR  = 4;
constexpr int BS  = 512;                // neurons per block = bucket size
constexpr int NCH = 256;                // partition chunks

// ---------------- init: zero masks + barrier slots ----------------
__global__ void init_misc(unsigned long long* __restrict__ mA,
                          unsigned long long* __restrict__ mB,
                          unsigned* __restrict__ barr, unsigned* __restrict__ rel,
                          int nmask, int nbar) {
    int i = blockIdx.x * blockDim.x + threadIdx.x;
    if (i < nmask) { mA[i] = 0ull; mB[i] = 0ull; }
    if (i < nbar)  { barr[i] = 0u; rel[i] = 0u; }
}

// ---------------- pass 1: per-chunk bucket histogram ----------------
__global__ void count_kernel(const int* __restrict__ post, int* __restrict__ ghist,
                             int E, int CH, int NBK) {
    __shared__ int h[256];                       // NBK <= 256
    for (int i = threadIdx.x; i < NBK; i += blockDim.x) h[i] = 0;
    __syncthreads();
    const int b = blockIdx.x, lo = b * CH, hi = min(lo + CH, E);
    for (int e = lo + threadIdx.x; e < hi; e += blockDim.x)
        atomicAdd(&h[post[e] >> 9], 1);          // LDS atomic: block-local
    __syncthreads();
    for (int i = threadIdx.x; i < NBK; i += blockDim.x)
        ghist[i * NCH + b] = h[i];               // bucket-major
}

// ---------------- pass 2a: tile-local exclusive scan (coalesced) -----------
__global__ void scanA_kernel(int* __restrict__ ghist, int* __restrict__ tilesum, int M) {
    __shared__ int s[1024];
    const int g = blockIdx.x * 1024 + threadIdx.x;
    int v = (g < M) ? ghist[g] : 0;
    s[threadIdx.x] = v;
    __syncthreads();
    for (int off = 1; off < 1024; off <<= 1) {
        int t = (threadIdx.x >= (unsigned)off) ? s[threadIdx.x - off] : 0;
        __syncthreads();
        s[threadIdx.x] += t;
        __syncthreads();
    }
    if (g < M) ghist[g] = s[threadIdx.x] - v;    // tile-local exclusive
    if (threadIdx.x == 1023) tilesum[blockIdx.x] = s[1023];
}

// ---------------- pass 2b: scan tile sums + emit bstart ----------------
__global__ void scanB_kernel(const int* __restrict__ tilesum, int* __restrict__ tileoff,
                             const int* __restrict__ ghist, int* __restrict__ bstart,
                             int NT, int NBK, int E) {
    __shared__ int s[256];
    __shared__ int toff[256];
    const int tid = threadIdx.x;
    int v = (tid < NT) ? tilesum[tid] : 0;
    s[tid] = v;
    __syncthreads();
    for (int off = 1; off < 256; off <<= 1) {
        int t = (tid >= off) ? s[tid - off] : 0;
        __syncthreads();
        s[tid] += t;
        __syncthreads();
    }
    if (tid < NT) { int e = s[tid] - v; toff[tid] = e; tileoff[tid] = e; }
    __syncthreads();
    if (tid < NBK) bstart[tid] = ghist[tid * NCH] + toff[(tid * NCH) >> 10];
    if (tid == 0)  bstart[NBK] = E;
}

// ---------------- pass 3: fill with block-local LDS cursors ----------------
// edge record: { pre(18b) | rc<<18 | local_idx<<20 , w }  -> ed.x>>18 = lidx*4+rc
__global__ void fill_kernel(const int* __restrict__ pre, const int* __restrict__ post,
                            const int* __restrict__ rc, const float* __restrict__ w,
                            const int* __restrict__ ghist, const int* __restrict__ tileoff,
                            uint2* __restrict__ ebuf, int E, int CH, int NBK) {
    __shared__ int cur[256];
    const int b = blockIdx.x;
    for (int i = threadIdx.x; i < NBK; i += blockDim.x) {
        int idx = i * NCH + b;
        cur[i] = ghist[idx] + tileoff[idx >> 10];
    }
    __syncthreads();
    const int lo = b * CH, hi = min(lo + CH, E);
    for (int e = lo + threadIdx.x; e < hi; e += blockDim.x) {
        int pn = post[e];
        int k = atomicAdd(&cur[pn >> 9], 1);     // LDS atomic: block-local
        ebuf[k] = make_uint2((unsigned)pre[e] | ((unsigned)rc[e] << 18)
                             | ((unsigned)(pn & (BS - 1)) << 20),
                             __float_as_uint(w[e]));
    }
}

// ---------------- persistent sim: all T steps, one barrier/step ------------
__global__ void __launch_bounds__(BS)
sim_kernel(const float4* __restrict__ x_ext4,
           const float* __restrict__ v0,  const float* __restrict__ v_th,
           const float* __restrict__ v_rst, const float* __restrict__ t_rf,
           const float* __restrict__ decay, const float* __restrict__ curf,
           const float* __restrict__ e_l,
           const float2* __restrict__ aamps, const float2* __restrict__ adec,
           const float* __restrict__ syn_d4, const float* __restrict__ psc_i4,
           const uint2* __restrict__ ebuf, const int* __restrict__ bstart,
           unsigned long long* __restrict__ mA, unsigned long long* __restrict__ mB,
           unsigned* __restrict__ barr, unsigned* __restrict__ rel,
           float* __restrict__ out, int N, int nmask, int T)
{
    extern __shared__ unsigned long long sdyn[];
    unsigned long long* smask = sdyn;            // nmask u64 (12.5 KB)
    float* sacc = (float*)(sdyn + nmask);        // BS*4 floats (8 KB)
    const int tid = threadIdx.x;
    const int n = blockIdx.x * BS + tid;
    const bool own = n < N;
    const unsigned nblk = gridDim.x;

    // ---- per-neuron state + params: registers for the whole run ----
    float psc0 = 0.f, psc1 = 0.f, psc2 = 0.f, psc3 = 0.f;
    float pr0 = 0.f, pr1 = 0.f, pr2 = 0.f, pr3 = 0.f;
    float vv = 0.f, rr_ = 0.f, zz = 0.f, a0 = 0.f, a1 = 0.f;
    float vth = 1.f, dvr = 0.f, trf = 0.f, dec = 0.f, cf = 0.f, el = 0.f;
    float aa0 = 0.f, aa1 = 0.f, ad0 = 0.f, ad1 = 0.f;
    if (own) {
        vv  = v0[n];
        vth = v_th[n];  dvr = v_rst[n] - vth;
        trf = t_rf[n];  dec = decay[n];
        cf  = curf[n];  el  = e_l[n];
        float2 aa = aamps[n]; aa0 = aa.x; aa1 = aa.y;
        float2 ad = adec[n];  ad0 = ad.x; ad1 = ad.y;
    }
    const float sd0 = syn_d4[0], sd1 = syn_d4[1], sd2 = syn_d4[2], sd3 = syn_d4[3];
    const float pi0 = psc_i4[0], pi1 = psc_i4[1], pi2 = psc_i4[2], pi3 = psc_i4[3];
    const int s_edge = bstart[blockIdx.x], e_edge = bstart[blockIdx.x + 1];

    for (int t = 0; t < T; ++t) {
        // x_t load issued early; consumed after the edge phase
        float4 xt = own ? x_ext4[(size_t)t * N + n] : make_float4(0.f, 0.f, 0.f, 0.f);

#pragma unroll
        for (int j = 0; j < RR; j++) sacc[tid + j * BS] = 0.f;

        if (t > 0) {
            // stage prev-step mask: relaxed scoped (MALL-coherent) loads.
            // ~3 loads/thread; everything else this kernel touches per step
            // is block-private and stays normally cached (no fences, ever).
            const unsigned long long* gm = ((t - 1) & 1) ? mB : mA;
            bool any = false;
            for (int i = tid; i < nmask; i += BS) {
                unsigned long long m = __hip_atomic_load(&gm[i], __ATOMIC_RELAXED,
                                                         __HIP_MEMORY_SCOPE_AGENT);
                smask[i] = m;
                any |= (m != 0ull);
            }
            int anyspk = __syncthreads_or(any ? 1 : 0);
            if (anyspk) {
                for (int j = s_edge + tid; j < e_edge; j += BS) {
                    uint2 ed = ebuf[j];
                    unsigned p = ed.x & 0x3FFFFu;
                    if ((smask[p >> 6] >> (p & 63)) & 1ull)
                        atomicAdd(&sacc[ed.x >> 18], __uint_as_float(ed.y));
                }
            }
        }
        __syncthreads();

        // ---- dense neuron update (state in registers) ----
        float nz = 0.f;
        if (own) {
            float acc0 = sacc[tid * 4 + 0], acc1 = sacc[tid * 4 + 1];
            float acc2 = sacc[tid * 4 + 2], acc3 = sacc[tid * 4 + 3];
            float i0 = acc0 + xt.x, i1 = acc1 + xt.y, i2 = acc2 + xt.z, i3 = acc3 + xt.w;
            float npr0 = pr0 * sd0 + i0 * pi0;
            float npr1 = pr1 * sd1 + i1 * pi1;
            float npr2 = pr2 * sd2 + i2 * pi2;
            float npr3 = pr3 * sd3 + i3 * pi3;
            float npc0 = psc0 * sd0 + sd0 * pr0;   // OLD psc_rise, DT=1
            float npc1 = psc1 * sd1 + sd1 * pr1;
            float npc2 = psc2 * sd2 + sd2 * pr2;
            float npc3 = psc3 * sd3 + sd3 * pr3;
            float in_cur = npc0 + npc1 + npc2 + npc3;
            psc0 = npc0; psc1 = npc1; psc2 = npc2; psc3 = npc3;
            pr0 = npr0; pr1 = npr1; pr2 = npr2; pr3 = npr3;

            float asum = a0 + a1;                  // OLD asc sum
            a0 = ad0 * a0 + zz * aa0;
            a1 = ad1 * a1 + zz * aa1;

            float nv = dec * vv + cf * (in_cur + asum + el) + zz * dvr;
            nz = (nv > vth) ? 1.f : 0.f;
            if (rr_ > 0.f) nz = 0.f;               // refractory mask (OLD r)
            rr_ = fmaxf(rr_ - 1.f + nz * trf, 0.f);
            vv = nv; zz = nz;
            out[(size_t)t * N + n] = nz;           // cached; flushed at kernel end
        }

        // publish this step's mask word (uncached store; one per wave)
        unsigned long long bal = __ballot(nz > 0.f);
        unsigned long long* gmo = (t & 1) ? mB : mA;
        if (own && (tid & 63) == 0)
            __hip_atomic_store(&gmo[n >> 6], bal, __ATOMIC_RELAXED,
                               __HIP_MEMORY_SCOPE_AGENT);

        if (t + 1 < T) {
            // drain this wave's mask stores to MALL, then grid barrier.
            asm volatile("s_waitcnt vmcnt(0)" ::: "memory");
            __syncthreads();
            if (tid == 0) {
                unsigned old = __hip_atomic_fetch_add(&barr[(size_t)t * 16], 1u,
                                   __ATOMIC_RELAXED, __HIP_MEMORY_SCOPE_AGENT);
                if (old == nblk - 1u) {
                    __hip_atomic_store(&rel[(size_t)t * 16], 1u,
                                       __ATOMIC_RELAXED, __HIP_MEMORY_SCOPE_AGENT);
                } else {
                    while (!__hip_atomic_load(&rel[(size_t)t * 16], __ATOMIC_RELAXED,
                                              __HIP_MEMORY_SCOPE_AGENT))
                        __builtin_amdgcn_s_sleep(4);
                }
            }
            __syncthreads();
        }
    }
}

// ---------------- launch ----------------
extern "C" void kernel_launch(void* const* d_in, const int* in_sizes, int n_in,
                              void* d_out, int out_size, void* d_ws, size_t ws_size,
                              hipStream_t stream) {
    const float* w_rec = (const float*)d_in[0];
    const float* x_ext = (const float*)d_in[1];
    const float* v0    = (const float*)d_in[2];
    const float* v_th  = (const float*)d_in[3];
    const float* v_rst = (const float*)d_in[4];
    const float* t_rf  = (const float*)d_in[5];
    const float* decay = (const float*)d_in[6];
    const float* curf  = (const float*)d_in[7];
    const float* e_l   = (const float*)d_in[8];
    const float* aamps = (const float*)d_in[9];
    const float* adec  = (const float*)d_in[10];
    const float* syn_d = (const float*)d_in[11];
    const float* psc_i = (const float*)d_in[12];
    const int*   pre   = (const int*)d_in[13];
    const int*   post  = (const int*)d_in[14];
    const int*   rc    = (const int*)d_in[15];

    const int E = in_sizes[0];
    const int N = in_sizes[2];            // B == 1
    const int T = in_sizes[1] / (N * RR);
    const int nmask = (N + 63) / 64;
    const int NBK = (N + BS - 1) / BS;    // buckets == sim blocks (196 <= 256)
    const int CH  = (E + NCH - 1) / NCH;
    const int M   = NBK * NCH;
    const int NT  = (M + 1023) / 1024;    // scan tiles (49)
    const int nbar = 16 * T;              // one 64B slot per step

    // -------- workspace layout --------
    char* ws = (char*)d_ws;
    uint2*  ebuf     = (uint2*)ws;                        ws += (size_t)E * 8;
    unsigned long long* maskA = (unsigned long long*)ws;  ws += (size_t)nmask * 8;
    unsigned long long* maskB = (unsigned long long*)ws;  ws += (size_t)nmask * 8;
    int* ghist       = (int*)ws;                          ws += (size_t)M * 4;
    int* tilesum     = (int*)ws;                          ws += (size_t)NT * 4;
    int* tileoff     = (int*)ws;                          ws += (size_t)NT * 4;
    int* bstart      = (int*)ws;                          ws += (size_t)(NBK + 1) * 4;
    unsigned* barr   = (unsigned*)ws;                     ws += (size_t)nbar * 4;
    unsigned* rel    = (unsigned*)ws;                     /* +nbar*4 */

    // -------- setup (5 dispatches, contention-free) --------
    const int initn = (nmask > nbar) ? nmask : nbar;
    init_misc<<<(initn + 255) / 256, 256, 0, stream>>>(maskA, maskB, barr, rel, nmask, nbar);
    count_kernel<<<NCH, 256, 0, stream>>>(post, ghist, E, CH, NBK);
    scanA_kernel<<<NT, 1024, 0, stream>>>(ghist, tilesum, M);
    scanB_kernel<<<1, 256, 0, stream>>>(tilesum, tileoff, ghist, bstart, NT, NBK, E);
    fill_kernel<<<NCH, 256, 0, stream>>>(pre, post, rc, w_rec, ghist, tileoff,
                                         ebuf, E, CH, NBK);

    // -------- persistent sim: 196 blocks, guaranteed co-resident --------
    const size_t smbytes = (size_t)nmask * 8 + (size_t)BS * RR * 4;  // ~20.7 KB
    sim_kernel<<<NBK, BS, smbytes, stream>>>(
        (const float4*)x_ext, v0, v_th, v_rst, t_rf, decay, curf, e_l,
        (const float2*)aamps, (const float2*)adec, syn_d, psc_i,
        ebuf, bstart, maskA, maskB, barr, rel,
        (float*)d_out, N, nmask, T);
}

// Round 8
// 574.268 us; speedup vs baseline: 3.3457x; 1.2331x over previous
//
#include <hip/hip_runtime.h>

// Billeh column GLIF forward — persistent step loop over block-bucketed edges.
//
// R7 measured 10.3us/step with the edge phase latency-bound (1 block/CU,
// 20 serial stride-512 uint2 loads/thread, VALUBusy 7.4%). This round keeps
// the validated structure (register state, relaxed-atomic mask exchange,
// fence-free 1-barrier/step) and attacks edge-phase latency:
//  - 196 blocks x 1024 threads (16 waves/CU, same guaranteed co-residency),
//  - SoA edges: epack[] u32 + ew[] f32, buckets padded to x4 records so each
//    thread tests 4 edges per uint4 load; weight loaded only on mask hit,
//  - x_t prefetch for t+1 issued before the barrier (HBM latency hidden).

constexpr int RR  = 4;
constexpr int BS  = 1024;               // threads per block
constexpr int BKN = 512;                // neurons per block (bucket size)
constexpr int NCH = 256;                // partition chunks

// ---------------- init: zero masks + barrier slots ----------------
__global__ void init_misc(unsigned long long* __restrict__ mA,
                          unsigned long long* __restrict__ mB,
                          unsigned* __restrict__ barr, unsigned* __restrict__ rel,
                          int nmask, int nbar) {
    int i = blockIdx.x * blockDim.x + threadIdx.x;
    if (i < nmask) { mA[i] = 0ull; mB[i] = 0ull; }
    if (i < nbar)  { barr[i] = 0u; rel[i] = 0u; }
}

// ---------------- pass 1: per-chunk bucket histogram ----------------
__global__ void count_kernel(const int* __restrict__ post, int* __restrict__ ghist,
                             int E, int CH, int NBK) {
    __shared__ int h[256];                       // NBK <= 256
    for (int i = threadIdx.x; i < NBK; i += blockDim.x) h[i] = 0;
    __syncthreads();
    const int b = blockIdx.x, lo = b * CH, hi = min(lo + CH, E);
    for (int e = lo + threadIdx.x; e < hi; e += blockDim.x)
        atomicAdd(&h[post[e] >> 9], 1);          // LDS atomic: block-local
    __syncthreads();
    for (int i = threadIdx.x; i < NBK; i += blockDim.x)
        ghist[i * NCH + b] = h[i];               // bucket-major
}

// ---------------- pass 2a: per-bucket scan over chunks ----------------
// block i: exclusive scan of ghist[i][0..NCH) in place; emit padded total.
__global__ void scanA_kernel(int* __restrict__ ghist, int* __restrict__ rtot,
                             int* __restrict__ ptot) {
    __shared__ int s[NCH];
    const int i = blockIdx.x, tid = threadIdx.x;
    int v = ghist[i * NCH + tid];
    s[tid] = v;
    __syncthreads();
    for (int off = 1; off < NCH; off <<= 1) {
        int t = (tid >= off) ? s[tid - off] : 0;
        __syncthreads();
        s[tid] += t;
        __syncthreads();
    }
    ghist[i * NCH + tid] = s[tid] - v;           // within-bucket exclusive
    if (tid == NCH - 1) {
        int tot = s[tid];
        rtot[i] = tot;
        ptot[i] = (tot + 3) & ~3;                // pad to x4 records
    }
}

// ---------------- pass 2b: scan padded totals -> bstart; zero pad slots ----
__global__ void scanB_kernel(const int* __restrict__ rtot, const int* __restrict__ ptot,
                             int* __restrict__ bstart,
                             unsigned* __restrict__ epack, float* __restrict__ ew,
                             int NBK) {
    __shared__ int s[256];
    const int tid = threadIdx.x;
    int v = (tid < NBK) ? ptot[tid] : 0;
    s[tid] = v;
    __syncthreads();
    for (int off = 1; off < 256; off <<= 1) {
        int t = (tid >= off) ? s[tid - off] : 0;
        __syncthreads();
        s[tid] += t;
        __syncthreads();
    }
    if (tid < NBK) bstart[tid] = s[tid] - v;
    if (tid == NBK - 1) bstart[NBK] = s[tid];
    __syncthreads();
    if (tid < NBK) {                              // zero the <=3 pad records
        int base = bstart[tid];
        for (int k = base + rtot[tid]; k < base + ptot[tid]; ++k) {
            epack[k] = 0u; ew[k] = 0.f;           // w=0 -> harmless if gated in
        }
    }
}

// ---------------- pass 3: fill with block-local LDS cursors ----------------
// record: epack = pre(18b) | rc<<18 | lidx<<20 ; ew = weight
__global__ void fill_kernel(const int* __restrict__ pre, const int* __restrict__ post,
                            const int* __restrict__ rc, const float* __restrict__ w,
                            const int* __restrict__ ghist, const int* __restrict__ bstart,
                            unsigned* __restrict__ epack, float* __restrict__ ew,
                            int E, int CH, int NBK) {
    __shared__ int cur[256];
    const int b = blockIdx.x;
    for (int i = threadIdx.x; i < NBK; i += blockDim.x)
        cur[i] = bstart[i] + ghist[i * NCH + b];
    __syncthreads();
    const int lo = b * CH, hi = min(lo + CH, E);
    for (int e = lo + threadIdx.x; e < hi; e += blockDim.x) {
        int pn = post[e];
        int k = atomicAdd(&cur[pn >> 9], 1);     // LDS atomic: block-local
        epack[k] = (unsigned)pre[e] | ((unsigned)rc[e] << 18)
                 | ((unsigned)(pn & (BKN - 1)) << 20);
        ew[k] = w[e];
    }
}

// ---------------- persistent sim: all T steps, one barrier/step ------------
__global__ void __launch_bounds__(BS)
sim_kernel(const float4* __restrict__ x_ext4,
           const float* __restrict__ v0,  const float* __restrict__ v_th,
           const float* __restrict__ v_rst, const float* __restrict__ t_rf,
           const float* __restrict__ decay, const float* __restrict__ curf,
           const float* __restrict__ e_l,
           const float2* __restrict__ aamps, const float2* __restrict__ adec,
           const float* __restrict__ syn_d4, const float* __restrict__ psc_i4,
           const uint4* __restrict__ epack4, const float* __restrict__ ew,
           const int* __restrict__ bstart,
           unsigned long long* __restrict__ mA, unsigned long long* __restrict__ mB,
           unsigned* __restrict__ barr, unsigned* __restrict__ rel,
           float* __restrict__ out, int N, int nmask, int T)
{
    extern __shared__ unsigned long long sdyn[];
    unsigned long long* smask = sdyn;            // nmask u64 (12.5 KB)
    float* sacc = (float*)(sdyn + nmask);        // BKN*4 floats (8 KB)
    const int tid = threadIdx.x;
    const int n = blockIdx.x * BKN + tid;        // owner mapping: tid < BKN
    const bool own = (tid < BKN) && (n < N);
    const unsigned nblk = gridDim.x;

    // ---- per-neuron state + params: registers for the whole run ----
    float psc0 = 0.f, psc1 = 0.f, psc2 = 0.f, psc3 = 0.f;
    float pr0 = 0.f, pr1 = 0.f, pr2 = 0.f, pr3 = 0.f;
    float vv = 0.f, rr_ = 0.f, zz = 0.f, a0 = 0.f, a1 = 0.f;
    float vth = 1.f, dvr = 0.f, trf = 0.f, dec = 0.f, cf = 0.f, el = 0.f;
    float aa0 = 0.f, aa1 = 0.f, ad0 = 0.f, ad1 = 0.f;
    if (own) {
        vv  = v0[n];
        vth = v_th[n];  dvr = v_rst[n] - vth;
        trf = t_rf[n];  dec = decay[n];
        cf  = curf[n];  el  = e_l[n];
        float2 aa = aamps[n]; aa0 = aa.x; aa1 = aa.y;
        float2 ad = adec[n];  ad0 = ad.x; ad1 = ad.y;
    }
    const float sd0 = syn_d4[0], sd1 = syn_d4[1], sd2 = syn_d4[2], sd3 = syn_d4[3];
    const float pi0 = psc_i4[0], pi1 = psc_i4[1], pi2 = psc_i4[2], pi3 = psc_i4[3];
    const int q_lo = bstart[blockIdx.x] >> 2;    // 4-aligned by construction
    const int q_hi = bstart[blockIdx.x + 1] >> 2;

    // prefetch x_t for t = 0
    float4 xt = own ? x_ext4[n] : make_float4(0.f, 0.f, 0.f, 0.f);

    for (int t = 0; t < T; ++t) {
        // stage prev-step mask (MALL-coherent loads) + zero accumulators
        bool any = false;
        if (t > 0) {
            const unsigned long long* gm = ((t - 1) & 1) ? mB : mA;
            for (int i = tid; i < nmask; i += BS) {
                unsigned long long m = __hip_atomic_load(&gm[i], __ATOMIC_RELAXED,
                                                         __HIP_MEMORY_SCOPE_AGENT);
                smask[i] = m;
                any |= (m != 0ull);
            }
        }
#pragma unroll
        for (int j = 0; j < 2; j++) sacc[tid + j * BS] = 0.f;
        int anyspk = __syncthreads_or(any ? 1 : 0);

        // ---- edge phase: 4 edges per uint4 load, weight fetched on hit ----
        if (anyspk) {
            for (int q = q_lo + tid; q < q_hi; q += BS) {
                uint4 pk = epack4[q];
                const int e0 = q << 2;
                unsigned p0_ = pk.x & 0x3FFFFu, p1_ = pk.y & 0x3FFFFu;
                unsigned p2_ = pk.z & 0x3FFFFu, p3_ = pk.w & 0x3FFFFu;
                if ((smask[p0_ >> 6] >> (p0_ & 63)) & 1ull)
                    atomicAdd(&sacc[pk.x >> 18], ew[e0 + 0]);
                if ((smask[p1_ >> 6] >> (p1_ & 63)) & 1ull)
                    atomicAdd(&sacc[pk.y >> 18], ew[e0 + 1]);
                if ((smask[p2_ >> 6] >> (p2_ & 63)) & 1ull)
                    atomicAdd(&sacc[pk.z >> 18], ew[e0 + 2]);
                if ((smask[p3_ >> 6] >> (p3_ & 63)) & 1ull)
                    atomicAdd(&sacc[pk.w >> 18], ew[e0 + 3]);
            }
        }
        __syncthreads();

        // ---- dense neuron update (state in registers) ----
        float nz = 0.f;
        if (own) {
            float acc0 = sacc[tid * 4 + 0], acc1 = sacc[tid * 4 + 1];
            float acc2 = sacc[tid * 4 + 2], acc3 = sacc[tid * 4 + 3];
            float i0 = acc0 + xt.x, i1 = acc1 + xt.y, i2 = acc2 + xt.z, i3 = acc3 + xt.w;
            float npr0 = pr0 * sd0 + i0 * pi0;
            float npr1 = pr1 * sd1 + i1 * pi1;
            float npr2 = pr2 * sd2 + i2 * pi2;
            float npr3 = pr3 * sd3 + i3 * pi3;
            float npc0 = psc0 * sd0 + sd0 * pr0;   // OLD psc_rise, DT=1
            float npc1 = psc1 * sd1 + sd1 * pr1;
            float npc2 = psc2 * sd2 + sd2 * pr2;
            float npc3 = psc3 * sd3 + sd3 * pr3;
            float in_cur = npc0 + npc1 + npc2 + npc3;
            psc0 = npc0; psc1 = npc1; psc2 = npc2; psc3 = npc3;
            pr0 = npr0; pr1 = npr1; pr2 = npr2; pr3 = npr3;

            float asum = a0 + a1;                  // OLD asc sum
            a0 = ad0 * a0 + zz * aa0;
            a1 = ad1 * a1 + zz * aa1;

            float nv = dec * vv + cf * (in_cur + asum + el) + zz * dvr;
            nz = (nv > vth) ? 1.f : 0.f;
            if (rr_ > 0.f) nz = 0.f;               // refractory mask (OLD r)
            rr_ = fmaxf(rr_ - 1.f + nz * trf, 0.f);
            vv = nv; zz = nz;
            out[(size_t)t * N + n] = nz;           // cached; flushed at kernel end
        }

        // prefetch x for t+1 NOW so HBM latency hides under drain+barrier
        float4 xtn = (own && t + 1 < T)
                   ? x_ext4[(size_t)(t + 1) * N + n]
                   : make_float4(0.f, 0.f, 0.f, 0.f);

        // publish this step's mask word (uncached store; one per wave)
        unsigned long long bal = __ballot(nz > 0.f);
        unsigned long long* gmo = (t & 1) ? mB : mA;
        if (own && (tid & 63) == 0)
            __hip_atomic_store(&gmo[n >> 6], bal, __ATOMIC_RELAXED,
                               __HIP_MEMORY_SCOPE_AGENT);

        if (t + 1 < T) {
            // drain this wave's mask stores (and prefetches), then grid barrier
            asm volatile("s_waitcnt vmcnt(0)" ::: "memory");
            __syncthreads();
            if (tid == 0) {
                unsigned old = __hip_atomic_fetch_add(&barr[(size_t)t * 16], 1u,
                                   __ATOMIC_RELAXED, __HIP_MEMORY_SCOPE_AGENT);
                if (old == nblk - 1u) {
                    __hip_atomic_store(&rel[(size_t)t * 16], 1u,
                                       __ATOMIC_RELAXED, __HIP_MEMORY_SCOPE_AGENT);
                } else {
                    while (!__hip_atomic_load(&rel[(size_t)t * 16], __ATOMIC_RELAXED,
                                              __HIP_MEMORY_SCOPE_AGENT))
                        __builtin_amdgcn_s_sleep(4);
                }
            }
            __syncthreads();
        }
        xt = xtn;
    }
}

// ---------------- launch ----------------
extern "C" void kernel_launch(void* const* d_in, const int* in_sizes, int n_in,
                              void* d_out, int out_size, void* d_ws, size_t ws_size,
                              hipStream_t stream) {
    const float* w_rec = (const float*)d_in[0];
    const float* x_ext = (const float*)d_in[1];
    const float* v0    = (const float*)d_in[2];
    const float* v_th  = (const float*)d_in[3];
    const float* v_rst = (const float*)d_in[4];
    const float* t_rf  = (const float*)d_in[5];
    const float* decay = (const float*)d_in[6];
    const float* curf  = (const float*)d_in[7];
    const float* e_l   = (const float*)d_in[8];
    const float* aamps = (const float*)d_in[9];
    const float* adec  = (const float*)d_in[10];
    const float* syn_d = (const float*)d_in[11];
    const float* psc_i = (const float*)d_in[12];
    const int*   pre   = (const int*)d_in[13];
    const int*   post  = (const int*)d_in[14];
    const int*   rc    = (const int*)d_in[15];

    const int E = in_sizes[0];
    const int N = in_sizes[2];            // B == 1
    const int T = in_sizes[1] / (N * RR);
    const int nmask = (N + 63) / 64;
    const int NBK = (N + BKN - 1) / BKN;  // buckets == sim blocks (196)
    const int CH  = (E + NCH - 1) / NCH;
    const int nbar = 16 * T;
    const int EP  = E + 4 * NBK;          // padded edge capacity

    // -------- workspace layout --------
    char* ws = (char*)d_ws;
    unsigned* epack  = (unsigned*)ws;                     ws += (size_t)EP * 4;
    float*    ew     = (float*)ws;                        ws += (size_t)EP * 4;
    unsigned long long* maskA = (unsigned long long*)ws;  ws += (size_t)nmask * 8;
    unsigned long long* maskB = (unsigned long long*)ws;  ws += (size_t)nmask * 8;
    int* ghist       = (int*)ws;                          ws += (size_t)NBK * NCH * 4;
    int* rtot        = (int*)ws;                          ws += (size_t)NBK * 4;
    int* ptot        = (int*)ws;                          ws += (size_t)NBK * 4;
    int* bstart      = (int*)ws;                          ws += (size_t)(NBK + 1) * 4;
    unsigned* barr   = (unsigned*)ws;                     ws += (size_t)nbar * 4;
    unsigned* rel    = (unsigned*)ws;                     /* +nbar*4 */

    // -------- setup (5 dispatches, contention-free) --------
    const int initn = (nmask > nbar) ? nmask : nbar;
    init_misc<<<(initn + 255) / 256, 256, 0, stream>>>(maskA, maskB, barr, rel,
                                                       nmask, nbar);
    count_kernel<<<NCH, 256, 0, stream>>>(post, ghist, E, CH, NBK);
    scanA_kernel<<<NBK, NCH, 0, stream>>>(ghist, rtot, ptot);
    scanB_kernel<<<1, 256, 0, stream>>>(rtot, ptot, bstart, epack, ew, NBK);
    fill_kernel<<<NCH, 256, 0, stream>>>(pre, post, rc, w_rec, ghist, bstart,
                                         epack, ew, E, CH, NBK);

    // -------- persistent sim: 196 blocks x 1024, guaranteed co-resident ----
    const size_t smbytes = (size_t)nmask * 8 + (size_t)BKN * RR * 4;  // ~20.5 KB
    sim_kernel<<<NBK, BS, smbytes, stream>>>(
        (const float4*)x_ext, v0, v_th, v_rst, t_rf, decay, curf, e_l,
        (const float2*)aamps, (const float2*)adec, syn_d, psc_i,
        (const uint4*)epack, ew, bstart, maskA, maskB, barr, rel,
        (float*)d_out, N, nmask, T);
}

// Round 9
// 504.018 us; speedup vs baseline: 3.8120x; 1.1394x over previous
//
#include <hip/hip_runtime.h>

// Billeh column GLIF forward — persistent kernel, edges resident in REGISTERS.
//
// R8 measured 7.3us/step, latency-chain bound: barrier release -> mask MALL
// loads -> edge L2 loads -> tests -> update -> drain -> 196 serialized RMW
// arrivals. This round:
//  - Edge data is CONSTANT across steps and only ~10 edges/thread: preload
//    ~2.5 uint4 quads + float4 weights into registers ONCE before the t-loop.
//    Hot-loop edge phase = in-register tests + LDS atomics, zero global loads.
//  - Hierarchical barrier arrival: 8 padded group counters + top counter +
//    single release word (25 serialized RMWs instead of 196).
//  - out-store and x_t prefetch issued in the barrier shadow (after drain,
//    before arrival), so their latency never sits on the critical path.
//  - Setup: init folded into count; 512 partition chunks.

constexpr int RR  = 4;
constexpr int BS  = 1024;               // threads per block
constexpr int BKN = 512;                // neurons per block (bucket size)
constexpr int NCH = 512;                // partition chunks

// ---------------- pass 1: per-chunk bucket histogram (+ misc zeroing) ------
__global__ void count_kernel(const int* __restrict__ post, int* __restrict__ ghist,
                             unsigned long long* __restrict__ mA,
                             unsigned long long* __restrict__ mB,
                             unsigned* __restrict__ barr,
                             int E, int CH, int NBK, int nmask, int nbar) {
    __shared__ int h[256];                       // NBK <= 256
    for (int i = threadIdx.x; i < NBK; i += blockDim.x) h[i] = 0;
    __syncthreads();
    const int b = blockIdx.x, lo = b * CH, hi = min(lo + CH, E);
    for (int e = lo + threadIdx.x; e < hi; e += blockDim.x)
        atomicAdd(&h[post[e] >> 9], 1);          // LDS atomic: block-local
    __syncthreads();
    for (int i = threadIdx.x; i < NBK; i += blockDim.x)
        ghist[i * NCH + b] = h[i];               // bucket-major
    // fold in one-time zeroing (grid-stride over masks + barrier slots)
    int g = blockIdx.x * blockDim.x + threadIdx.x;
    int gs = gridDim.x * blockDim.x;
    for (int i = g; i < nmask; i += gs) { mA[i] = 0ull; mB[i] = 0ull; }
    for (int i = g; i < nbar; i += gs) barr[i] = 0u;
}

// ---------------- pass 2a: per-bucket exclusive scan over chunks -----------
__global__ void scanA_kernel(int* __restrict__ ghist, int* __restrict__ rtot,
                             int* __restrict__ ptot) {
    __shared__ int s[NCH];
    const int i = blockIdx.x, tid = threadIdx.x;
    int v = ghist[i * NCH + tid];
    s[tid] = v;
    __syncthreads();
    for (int off = 1; off < NCH; off <<= 1) {
        int t = (tid >= off) ? s[tid - off] : 0;
        __syncthreads();
        s[tid] += t;
        __syncthreads();
    }
    ghist[i * NCH + tid] = s[tid] - v;           // within-bucket exclusive
    if (tid == NCH - 1) {
        int tot = s[tid];
        rtot[i] = tot;
        ptot[i] = (tot + 3) & ~3;                // pad to x4 records
    }
}

// ---------------- pass 2b: scan padded totals -> bstart; zero pad slots ----
__global__ void scanB_kernel(const int* __restrict__ rtot, const int* __restrict__ ptot,
                             int* __restrict__ bstart,
                             unsigned* __restrict__ epack, float* __restrict__ ew,
                             int NBK) {
    __shared__ int s[256];
    const int tid = threadIdx.x;
    int v = (tid < NBK) ? ptot[tid] : 0;
    s[tid] = v;
    __syncthreads();
    for (int off = 1; off < 256; off <<= 1) {
        int t = (tid >= off) ? s[tid - off] : 0;
        __syncthreads();
        s[tid] += t;
        __syncthreads();
    }
    if (tid < NBK) bstart[tid] = s[tid] - v;
    if (tid == NBK - 1) bstart[NBK] = s[tid];
    __syncthreads();
    if (tid < NBK) {                              // zero the <=3 pad records
        int base = bstart[tid];
        for (int k = base + rtot[tid]; k < base + ptot[tid]; ++k) {
            epack[k] = 0u; ew[k] = 0.f;           // pre=0,w=0 -> harmless
        }
    }
}

// ---------------- pass 3: fill with block-local LDS cursors ----------------
// record: epack = pre(18b) | rc<<18 | lidx<<20 ; ew = weight
__global__ void fill_kernel(const int* __restrict__ pre, const int* __restrict__ post,
                            const int* __restrict__ rc, const float* __restrict__ w,
                            const int* __restrict__ ghist, const int* __restrict__ bstart,
                            unsigned* __restrict__ epack, float* __restrict__ ew,
                            int E, int CH, int NBK) {
    __shared__ int cur[256];
    const int b = blockIdx.x;
    for (int i = threadIdx.x; i < NBK; i += blockDim.x)
        cur[i] = bstart[i] + ghist[i * NCH + b];
    __syncthreads();
    const int lo = b * CH, hi = min(lo + CH, E);
    for (int e = lo + threadIdx.x; e < hi; e += blockDim.x) {
        int pn = post[e];
        int k = atomicAdd(&cur[pn >> 9], 1);     // LDS atomic: block-local
        epack[k] = (unsigned)pre[e] | ((unsigned)rc[e] << 18)
                 | ((unsigned)(pn & (BKN - 1)) << 20);
        ew[k] = w[e];
    }
}

// ---------------- persistent sim ----------------
__device__ __forceinline__ void test4(const uint4 pk, const float4 wv,
                                      const unsigned long long* smask,
                                      float* sacc) {
    unsigned a = pk.x & 0x3FFFFu, b = pk.y & 0x3FFFFu;
    unsigned c = pk.z & 0x3FFFFu, d = pk.w & 0x3FFFFu;
    if ((smask[a >> 6] >> (a & 63)) & 1ull) atomicAdd(&sacc[pk.x >> 18], wv.x);
    if ((smask[b >> 6] >> (b & 63)) & 1ull) atomicAdd(&sacc[pk.y >> 18], wv.y);
    if ((smask[c >> 6] >> (c & 63)) & 1ull) atomicAdd(&sacc[pk.z >> 18], wv.z);
    if ((smask[d >> 6] >> (d & 63)) & 1ull) atomicAdd(&sacc[pk.w >> 18], wv.w);
}

__global__ void __launch_bounds__(BS, 4)
sim_kernel(const float4* __restrict__ x_ext4,
           const float* __restrict__ v0,  const float* __restrict__ v_th,
           const float* __restrict__ v_rst, const float* __restrict__ t_rf,
           const float* __restrict__ decay, const float* __restrict__ curf,
           const float* __restrict__ e_l,
           const float2* __restrict__ aamps, const float2* __restrict__ adec,
           const float* __restrict__ syn_d4, const float* __restrict__ psc_i4,
           const uint4* __restrict__ epack4, const float4* __restrict__ ew4,
           const int* __restrict__ bstart,
           unsigned long long* __restrict__ mA, unsigned long long* __restrict__ mB,
           unsigned* __restrict__ barr,
           float* __restrict__ out, int N, int nmask, int T)
{
    extern __shared__ unsigned long long sdyn[];
    unsigned long long* smask = sdyn;            // nmask u64 (12.5 KB)
    float* sacc = (float*)(sdyn + nmask);        // BKN*4 floats (8 KB)
    const int tid = threadIdx.x;
    const int n = blockIdx.x * BKN + tid;        // owner mapping: tid < BKN
    const bool own = (tid < BKN) && (n < N);
    const unsigned nblk = gridDim.x;

    // ---- per-neuron state + params: registers for the whole run ----
    float psc0 = 0.f, psc1 = 0.f, psc2 = 0.f, psc3 = 0.f;
    float pr0 = 0.f, pr1 = 0.f, pr2 = 0.f, pr3 = 0.f;
    float vv = 0.f, rr_ = 0.f, zz = 0.f, a0 = 0.f, a1 = 0.f;
    float vth = 1.f, dvr = 0.f, trf = 0.f, dec = 0.f, cf = 0.f, el = 0.f;
    float aa0 = 0.f, aa1 = 0.f, ad0 = 0.f, ad1 = 0.f;
    if (own) {
        vv  = v0[n];
        vth = v_th[n];  dvr = v_rst[n] - vth;
        trf = t_rf[n];  dec = decay[n];
        cf  = curf[n];  el  = e_l[n];
        float2 aa = aamps[n]; aa0 = aa.x; aa1 = aa.y;
        float2 ad = adec[n];  ad0 = ad.x; ad1 = ad.y;
    }
    const float sd0 = syn_d4[0], sd1 = syn_d4[1], sd2 = syn_d4[2], sd3 = syn_d4[3];
    const float pi0 = psc_i4[0], pi1 = psc_i4[1], pi2 = psc_i4[2], pi3 = psc_i4[3];

    // ---- preload this thread's edges into REGISTERS (constant across t) ----
    const int q_lo = bstart[blockIdx.x] >> 2;    // 4-aligned by construction
    const int q_hi = bstart[blockIdx.x + 1] >> 2;
    const int i0 = q_lo + tid, i1 = i0 + BS, i2 = i1 + BS, i3 = i2 + BS;
    const uint4 z4 = make_uint4(0u, 0u, 0u, 0u);
    const float4 zf = make_float4(0.f, 0.f, 0.f, 0.f);
    uint4  qa = (i0 < q_hi) ? epack4[i0] : z4;
    uint4  qb = (i1 < q_hi) ? epack4[i1] : z4;
    uint4  qc = (i2 < q_hi) ? epack4[i2] : z4;
    uint4  qd = (i3 < q_hi) ? epack4[i3] : z4;
    float4 wa = (i0 < q_hi) ? ew4[i0] : zf;
    float4 wb = (i1 < q_hi) ? ew4[i1] : zf;
    float4 wc = (i2 < q_hi) ? ew4[i2] : zf;
    float4 wd = (i3 < q_hi) ? ew4[i3] : zf;
    const bool overflow = (q_hi - q_lo) > 4 * BS;   // practically never

    const int g = blockIdx.x & 7;
    const unsigned gsize = (nblk - (unsigned)g + 7u) >> 3;

    // prefetch x_t for t = 0
    float4 xt = own ? x_ext4[n] : zf;

    for (int t = 0; t < T; ++t) {
        // ---- stage prev-step mask (MALL loads) + zero accumulators ----
        unsigned long long m0 = 0ull, m1 = 0ull;
        if (t > 0) {
            const unsigned long long* gm = ((t - 1) & 1) ? mB : mA;
            if (tid < nmask)
                m0 = __hip_atomic_load(&gm[tid], __ATOMIC_RELAXED,
                                       __HIP_MEMORY_SCOPE_AGENT);
            if (tid + BS < nmask)
                m1 = __hip_atomic_load(&gm[tid + BS], __ATOMIC_RELAXED,
                                       __HIP_MEMORY_SCOPE_AGENT);
        }
        sacc[tid] = 0.f; sacc[tid + BS] = 0.f;
        if (tid < nmask) smask[tid] = m0;
        if (tid + BS < nmask) smask[tid + BS] = m1;
        int anyspk = __syncthreads_or((m0 | m1) != 0ull ? 1 : 0);

        // ---- edge phase: in-register edges vs LDS mask, LDS atomics ----
        if (anyspk) {
            test4(qa, wa, smask, sacc);
            test4(qb, wb, smask, sacc);
            test4(qc, wc, smask, sacc);
            test4(qd, wd, smask, sacc);
            if (overflow) {
                for (int q = q_lo + tid + 4 * BS; q < q_hi; q += BS)
                    test4(epack4[q], ew4[q], smask, sacc);
            }
        }
        __syncthreads();

        // ---- dense neuron update (state in registers) ----
        float nz = 0.f;
        if (own) {
            float acc0 = sacc[tid * 4 + 0], acc1 = sacc[tid * 4 + 1];
            float acc2 = sacc[tid * 4 + 2], acc3 = sacc[tid * 4 + 3];
            float i0_ = acc0 + xt.x, i1_ = acc1 + xt.y;
            float i2_ = acc2 + xt.z, i3_ = acc3 + xt.w;
            float npr0 = pr0 * sd0 + i0_ * pi0;
            float npr1 = pr1 * sd1 + i1_ * pi1;
            float npr2 = pr2 * sd2 + i2_ * pi2;
            float npr3 = pr3 * sd3 + i3_ * pi3;
            float npc0 = psc0 * sd0 + sd0 * pr0;   // OLD psc_rise, DT=1
            float npc1 = psc1 * sd1 + sd1 * pr1;
            float npc2 = psc2 * sd2 + sd2 * pr2;
            float npc3 = psc3 * sd3 + sd3 * pr3;
            float in_cur = npc0 + npc1 + npc2 + npc3;
            psc0 = npc0; psc1 = npc1; psc2 = npc2; psc3 = npc3;
            pr0 = npr0; pr1 = npr1; pr2 = npr2; pr3 = npr3;

            float asum = a0 + a1;                  // OLD asc sum
            a0 = ad0 * a0 + zz * aa0;
            a1 = ad1 * a1 + zz * aa1;

            float nv = dec * vv + cf * (in_cur + asum + el) + zz * dvr;
            nz = (nv > vth) ? 1.f : 0.f;
            if (rr_ > 0.f) nz = 0.f;               // refractory mask (OLD r)
            rr_ = fmaxf(rr_ - 1.f + nz * trf, 0.f);
            vv = nv; zz = nz;
        }

        // publish this step's mask word (uncached store; one per wave)
        unsigned long long bal = __ballot(nz > 0.f);
        unsigned long long* gmo = (t & 1) ? mB : mA;
        if (own && (tid & 63) == 0)
            __hip_atomic_store(&gmo[n >> 6], bal, __ATOMIC_RELAXED,
                               __HIP_MEMORY_SCOPE_AGENT);

        if (t + 1 < T) {
            // drain mask store, then put out-store + x-prefetch in the
            // barrier shadow (they complete during arrival/poll).
            asm volatile("s_waitcnt vmcnt(0)" ::: "memory");
            if (own) out[(size_t)t * N + n] = nz;
            float4 xtn = own ? x_ext4[(size_t)(t + 1) * N + n] : zf;
            __syncthreads();
            if (tid == 0) {
                // hierarchical arrival: 8 padded group counters + top + release
                unsigned* bg  = barr + (size_t)t * 160 + (size_t)g * 16;
                unsigned* btp = barr + (size_t)t * 160 + 128;
                unsigned* rl  = barr + (size_t)t * 160 + 144;
                bool done = false;
                unsigned old = __hip_atomic_fetch_add(bg, 1u, __ATOMIC_RELAXED,
                                                      __HIP_MEMORY_SCOPE_AGENT);
                if (old == gsize - 1u) {
                    unsigned ot = __hip_atomic_fetch_add(btp, 1u, __ATOMIC_RELAXED,
                                                         __HIP_MEMORY_SCOPE_AGENT);
                    if (ot == 7u) {
                        __hip_atomic_store(rl, 1u, __ATOMIC_RELAXED,
                                           __HIP_MEMORY_SCOPE_AGENT);
                        done = true;
                    }
                }
                if (!done)
                    while (!__hip_atomic_load(rl, __ATOMIC_RELAXED,
                                              __HIP_MEMORY_SCOPE_AGENT))
                        __builtin_amdgcn_s_sleep(1);
            }
            __syncthreads();
            xt = xtn;
        } else {
            if (own) out[(size_t)t * N + n] = nz;  // final step: plain store
        }
    }
}

// ---------------- launch ----------------
extern "C" void kernel_launch(void* const* d_in, const int* in_sizes, int n_in,
                              void* d_out, int out_size, void* d_ws, size_t ws_size,
                              hipStream_t stream) {
    const float* w_rec = (const float*)d_in[0];
    const float* x_ext = (const float*)d_in[1];
    const float* v0    = (const float*)d_in[2];
    const float* v_th  = (const float*)d_in[3];
    const float* v_rst = (const float*)d_in[4];
    const float* t_rf  = (const float*)d_in[5];
    const float* decay = (const float*)d_in[6];
    const float* curf  = (const float*)d_in[7];
    const float* e_l   = (const float*)d_in[8];
    const float* aamps = (const float*)d_in[9];
    const float* adec  = (const float*)d_in[10];
    const float* syn_d = (const float*)d_in[11];
    const float* psc_i = (const float*)d_in[12];
    const int*   pre   = (const int*)d_in[13];
    const int*   post  = (const int*)d_in[14];
    const int*   rc    = (const int*)d_in[15];

    const int E = in_sizes[0];
    const int N = in_sizes[2];            // B == 1
    const int T = in_sizes[1] / (N * RR);
    const int nmask = (N + 63) / 64;
    const int NBK = (N + BKN - 1) / BKN;  // buckets == sim blocks (196)
    const int CH  = (E + NCH - 1) / NCH;
    const int nbar = 160 * T;             // per step: 8 group + top + release lines
    const int EP  = E + 4 * NBK;          // padded edge capacity

    // -------- workspace layout --------
    char* ws = (char*)d_ws;
    unsigned* epack  = (unsigned*)ws;                     ws += (size_t)EP * 4;
    float*    ew     = (float*)ws;                        ws += (size_t)EP * 4;
    unsigned long long* maskA = (unsigned long long*)ws;  ws += (size_t)nmask * 8;
    unsigned long long* maskB = (unsigned long long*)ws;  ws += (size_t)nmask * 8;
    int* ghist       = (int*)ws;                          ws += (size_t)NBK * NCH * 4;
    int* rtot        = (int*)ws;                          ws += (size_t)NBK * 4;
    int* ptot        = (int*)ws;                          ws += (size_t)NBK * 4;
    int* bstart      = (int*)ws;                          ws += (size_t)(NBK + 1) * 4;
    unsigned* barr   = (unsigned*)ws;                     /* +nbar*4 */

    // -------- setup (4 dispatches, contention-free) --------
    count_kernel<<<NCH, 256, 0, stream>>>(post, ghist, maskA, maskB, barr,
                                          E, CH, NBK, nmask, nbar);
    scanA_kernel<<<NBK, NCH, 0, stream>>>(ghist, rtot, ptot);
    scanB_kernel<<<1, 256, 0, stream>>>(rtot, ptot, bstart, epack, ew, NBK);
    fill_kernel<<<NCH, 256, 0, stream>>>(pre, post, rc, w_rec, ghist, bstart,
                                         epack, ew, E, CH, NBK);

    // -------- persistent sim: 196 blocks x 1024, 1 block/CU ----------------
    const size_t smbytes = (size_t)nmask * 8 + (size_t)BKN * RR * 4;  // ~20.5 KB
    sim_kernel<<<NBK, BS, smbytes, stream>>>(
        (const float4*)x_ext, v0, v_th, v_rst, t_rf, decay, curf, e_l,
        (const float2*)aamps, (const float2*)adec, syn_d, psc_i,
        (const uint4*)epack, (const float4*)ew, bstart, maskA, maskB, barr,
        (float*)d_out, N, nmask, T);
}

// Round 10
// 483.078 us; speedup vs baseline: 3.9773x; 1.0433x over previous
//
#include <hip/hip_runtime.h>

// Billeh column GLIF forward — persistent kernel, split-phase barrier.
//
// Key identity (from the reference): new_z depends only on OLD psc/psc_rise/
// asc/v/z/r — this step's inputs (rec_in + x_t) feed ONLY new_psc_rise.
// So each step: Phase A computes+publishes mask(t) FIRST and arrives at the
// barrier (non-blocking); Phase B consumes mask(t-1) (edge phase) and updates
// psc_rise; the barrier WAIT happens after Phase B, by which time the release
// chain has completed under useful work. The per-step MALL chain (store ->
// drain -> arrive -> release -> poll) is thus overlapped with compute.
// Everything else (register-resident edges, LDS mask+accumulators,
// hierarchical arrival, fence-free relaxed atomics) carried from R9.

constexpr int RR  = 4;
constexpr int BS  = 1024;               // threads per block
constexpr int BKN = 512;                // neurons per block (bucket size)
constexpr int NCH = 512;                // partition chunks

// ---------------- pass 1: per-chunk bucket histogram (+ misc zeroing) ------
__global__ void count_kernel(const int* __restrict__ post, int* __restrict__ ghist,
                             unsigned long long* __restrict__ mA,
                             unsigned long long* __restrict__ mB,
                             unsigned* __restrict__ barr,
                             int E, int CH, int NBK, int nmask, int nbar) {
    __shared__ int h[256];                       // NBK <= 256
    for (int i = threadIdx.x; i < NBK; i += blockDim.x) h[i] = 0;
    __syncthreads();
    const int b = blockIdx.x, lo = b * CH, hi = min(lo + CH, E);
    for (int e = lo + threadIdx.x; e < hi; e += blockDim.x)
        atomicAdd(&h[post[e] >> 9], 1);          // LDS atomic: block-local
    __syncthreads();
    for (int i = threadIdx.x; i < NBK; i += blockDim.x)
        ghist[i * NCH + b] = h[i];               // bucket-major
    int g = blockIdx.x * blockDim.x + threadIdx.x;
    int gs = gridDim.x * blockDim.x;
    for (int i = g; i < nmask; i += gs) { mA[i] = 0ull; mB[i] = 0ull; }
    for (int i = g; i < nbar; i += gs) barr[i] = 0u;
}

// ---------------- pass 2a: per-bucket exclusive scan over chunks -----------
__global__ void scanA_kernel(int* __restrict__ ghist, int* __restrict__ rtot,
                             int* __restrict__ ptot) {
    __shared__ int s[NCH];
    const int i = blockIdx.x, tid = threadIdx.x;
    int v = ghist[i * NCH + tid];
    s[tid] = v;
    __syncthreads();
    for (int off = 1; off < NCH; off <<= 1) {
        int t = (tid >= off) ? s[tid - off] : 0;
        __syncthreads();
        s[tid] += t;
        __syncthreads();
    }
    ghist[i * NCH + tid] = s[tid] - v;           // within-bucket exclusive
    if (tid == NCH - 1) {
        int tot = s[tid];
        rtot[i] = tot;
        ptot[i] = (tot + 3) & ~3;                // pad to x4 records
    }
}

// ---------------- pass 2b: scan padded totals -> bstart; zero pad slots ----
__global__ void scanB_kernel(const int* __restrict__ rtot, const int* __restrict__ ptot,
                             int* __restrict__ bstart,
                             unsigned* __restrict__ epack, float* __restrict__ ew,
                             int NBK) {
    __shared__ int s[256];
    const int tid = threadIdx.x;
    int v = (tid < NBK) ? ptot[tid] : 0;
    s[tid] = v;
    __syncthreads();
    for (int off = 1; off < 256; off <<= 1) {
        int t = (tid >= off) ? s[tid - off] : 0;
        __syncthreads();
        s[tid] += t;
        __syncthreads();
    }
    if (tid < NBK) bstart[tid] = s[tid] - v;
    if (tid == NBK - 1) bstart[NBK] = s[tid];
    __syncthreads();
    if (tid < NBK) {                              // zero the <=3 pad records
        int base = bstart[tid];
        for (int k = base + rtot[tid]; k < base + ptot[tid]; ++k) {
            epack[k] = 0u; ew[k] = 0.f;           // pre=0,w=0 -> harmless
        }
    }
}

// ---------------- pass 3: fill with block-local LDS cursors ----------------
// record: epack = pre(18b) | rc<<18 | lidx<<20 ; ew = weight
__global__ void fill_kernel(const int* __restrict__ pre, const int* __restrict__ post,
                            const int* __restrict__ rc, const float* __restrict__ w,
                            const int* __restrict__ ghist, const int* __restrict__ bstart,
                            unsigned* __restrict__ epack, float* __restrict__ ew,
                            int E, int CH, int NBK) {
    __shared__ int cur[256];
    const int b = blockIdx.x;
    for (int i = threadIdx.x; i < NBK; i += blockDim.x)
        cur[i] = bstart[i] + ghist[i * NCH + b];
    __syncthreads();
    const int lo = b * CH, hi = min(lo + CH, E);
    for (int e = lo + threadIdx.x; e < hi; e += blockDim.x) {
        int pn = post[e];
        int k = atomicAdd(&cur[pn >> 9], 1);     // LDS atomic: block-local
        epack[k] = (unsigned)pre[e] | ((unsigned)rc[e] << 18)
                 | ((unsigned)(pn & (BKN - 1)) << 20);
        ew[k] = w[e];
    }
}

// ---------------- persistent sim ----------------
__device__ __forceinline__ void test4(const uint4 pk, const float4 wv,
                                      const unsigned long long* smask,
                                      float* sacc) {
    unsigned a = pk.x & 0x3FFFFu, b = pk.y & 0x3FFFFu;
    unsigned c = pk.z & 0x3FFFFu, d = pk.w & 0x3FFFFu;
    if ((smask[a >> 6] >> (a & 63)) & 1ull) atomicAdd(&sacc[pk.x >> 18], wv.x);
    if ((smask[b >> 6] >> (b & 63)) & 1ull) atomicAdd(&sacc[pk.y >> 18], wv.y);
    if ((smask[c >> 6] >> (c & 63)) & 1ull) atomicAdd(&sacc[pk.z >> 18], wv.z);
    if ((smask[d >> 6] >> (d & 63)) & 1ull) atomicAdd(&sacc[pk.w >> 18], wv.w);
}

__global__ void __launch_bounds__(BS, 4)
sim_kernel(const float4* __restrict__ x_ext4,
           const float* __restrict__ v0,  const float* __restrict__ v_th,
           const float* __restrict__ v_rst, const float* __restrict__ t_rf,
           const float* __restrict__ decay, const float* __restrict__ curf,
           const float* __restrict__ e_l,
           const float2* __restrict__ aamps, const float2* __restrict__ adec,
           const float* __restrict__ syn_d4, const float* __restrict__ psc_i4,
           const uint4* __restrict__ epack4, const float4* __restrict__ ew4,
           const int* __restrict__ bstart,
           unsigned long long* __restrict__ mA, unsigned long long* __restrict__ mB,
           unsigned* __restrict__ barr,
           float* __restrict__ out, int N, int nmask, int T)
{
    extern __shared__ unsigned long long sdyn[];
    unsigned long long* smask = sdyn;            // nmask u64 (12.5 KB)
    float* sacc = (float*)(sdyn + nmask);        // BKN*4 floats (8 KB)
    const int tid = threadIdx.x;
    const int n = blockIdx.x * BKN + tid;        // owner mapping: tid < BKN
    const bool own = (tid < BKN) && (n < N);
    const unsigned nblk = gridDim.x;

    // ---- per-neuron state + params: registers for the whole run ----
    float psc0 = 0.f, psc1 = 0.f, psc2 = 0.f, psc3 = 0.f;
    float pr0 = 0.f, pr1 = 0.f, pr2 = 0.f, pr3 = 0.f;
    float vv = 0.f, rr_ = 0.f, zz = 0.f, a0 = 0.f, a1 = 0.f;
    float vth = 1.f, dvr = 0.f, trf = 0.f, dec = 0.f, cf = 0.f, el = 0.f;
    float aa0 = 0.f, aa1 = 0.f, ad0 = 0.f, ad1 = 0.f;
    if (own) {
        vv  = v0[n];
        vth = v_th[n];  dvr = v_rst[n] - vth;
        trf = t_rf[n];  dec = decay[n];
        cf  = curf[n];  el  = e_l[n];
        float2 aa = aamps[n]; aa0 = aa.x; aa1 = aa.y;
        float2 ad = adec[n];  ad0 = ad.x; ad1 = ad.y;
    }
    const float sd0 = syn_d4[0], sd1 = syn_d4[1], sd2 = syn_d4[2], sd3 = syn_d4[3];
    const float pi0 = psc_i4[0], pi1 = psc_i4[1], pi2 = psc_i4[2], pi3 = psc_i4[3];

    // ---- preload this thread's edges into REGISTERS (constant across t) ----
    const int q_lo = bstart[blockIdx.x] >> 2;    // 4-aligned by construction
    const int q_hi = bstart[blockIdx.x + 1] >> 2;
    const int i0 = q_lo + tid, i1 = i0 + BS, i2 = i1 + BS, i3 = i2 + BS;
    const uint4 z4 = make_uint4(0u, 0u, 0u, 0u);
    const float4 zf = make_float4(0.f, 0.f, 0.f, 0.f);
    uint4  qa = (i0 < q_hi) ? epack4[i0] : z4;
    uint4  qb = (i1 < q_hi) ? epack4[i1] : z4;
    uint4  qc = (i2 < q_hi) ? epack4[i2] : z4;
    uint4  qd = (i3 < q_hi) ? epack4[i3] : z4;
    float4 wa = (i0 < q_hi) ? ew4[i0] : zf;
    float4 wb = (i1 < q_hi) ? ew4[i1] : zf;
    float4 wc = (i2 < q_hi) ? ew4[i2] : zf;
    float4 wd = (i3 < q_hi) ? ew4[i3] : zf;
    const bool overflow = (q_hi - q_lo) > 4 * BS;   // practically never

    const int g = blockIdx.x & 7;
    const unsigned gsize = (nblk - (unsigned)g + 7u) >> 3;

    // ---- prologue: zero LDS mask + accumulators; prefetch x(0) ----
    for (int i = tid; i < nmask; i += BS) smask[i] = 0ull;
    sacc[tid] = 0.f; sacc[tid + BS] = 0.f;
    float4 xt = own ? x_ext4[n] : zf;
    int anyspk = 0;
    __syncthreads();

    for (int t = 0; t < T; ++t) {
        // ======== Phase A: spike decision (OLD state only) + publish ========
        float nz = 0.f;
        float npc0, npc1, npc2, npc3;
        if (own) {
            npc0 = psc0 * sd0 + sd0 * pr0;       // OLD psc_rise, DT=1
            npc1 = psc1 * sd1 + sd1 * pr1;
            npc2 = psc2 * sd2 + sd2 * pr2;
            npc3 = psc3 * sd3 + sd3 * pr3;
            float in_cur = npc0 + npc1 + npc2 + npc3;
            float asum = a0 + a1;                // OLD asc sum
            float nv = dec * vv + cf * (in_cur + asum + el) + zz * dvr;
            nz = (nv > vth) ? 1.f : 0.f;
            if (rr_ > 0.f) nz = 0.f;             // refractory mask (OLD r)
            rr_ = fmaxf(rr_ - 1.f + nz * trf, 0.f);
            a0 = ad0 * a0 + zz * aa0;            // asc update uses OLD z
            a1 = ad1 * a1 + zz * aa1;
            psc0 = npc0; psc1 = npc1; psc2 = npc2; psc3 = npc3;
            vv = nv;
        }
        const bool lastT = (t + 1 >= T);

        // publish mask(t) word (uncached store; one per wave)
        unsigned long long bal = __ballot(nz > 0.f);
        if (!lastT) {
            unsigned long long* gmo = (t & 1) ? mB : mA;
            if (own && (tid & 63) == 0)
                __hip_atomic_store(&gmo[n >> 6], bal, __ATOMIC_RELAXED,
                                   __HIP_MEMORY_SCOPE_AGENT);
            asm volatile("s_waitcnt vmcnt(0)" ::: "memory");
        }
        __syncthreads();                          // S1: all mask stores drained

        // non-blocking ARRIVAL (release chain completes under Phase B)
        bool i_released = false;
        if (!lastT && tid == 0) {
            unsigned* bg  = barr + (size_t)t * 160 + (size_t)g * 16;
            unsigned* btp = barr + (size_t)t * 160 + 128;
            unsigned* rl  = barr + (size_t)t * 160 + 144;
            unsigned old = __hip_atomic_fetch_add(bg, 1u, __ATOMIC_RELAXED,
                                                  __HIP_MEMORY_SCOPE_AGENT);
            if (old == gsize - 1u) {
                unsigned ot = __hip_atomic_fetch_add(btp, 1u, __ATOMIC_RELAXED,
                                                     __HIP_MEMORY_SCOPE_AGENT);
                if (ot == 7u) {
                    __hip_atomic_store(rl, 1u, __ATOMIC_RELAXED,
                                       __HIP_MEMORY_SCOPE_AGENT);
                    i_released = true;
                }
            }
        }

        // ======== Phase B: edge phase vs mask(t-1) + psc_rise update ========
        if (anyspk) {
            test4(qa, wa, smask, sacc);
            test4(qb, wb, smask, sacc);
            test4(qc, wc, smask, sacc);
            test4(qd, wd, smask, sacc);
            if (overflow) {
                for (int q = q_lo + tid + 4 * BS; q < q_hi; q += BS)
                    test4(epack4[q], ew4[q], smask, sacc);
            }
        }
        __syncthreads();                          // S2: edge writes visible

        if (own) {
            float acc0 = sacc[tid * 4 + 0], acc1 = sacc[tid * 4 + 1];
            float acc2 = sacc[tid * 4 + 2], acc3 = sacc[tid * 4 + 3];
            sacc[tid * 4 + 0] = 0.f; sacc[tid * 4 + 1] = 0.f;  // re-zero own slots
            sacc[tid * 4 + 2] = 0.f; sacc[tid * 4 + 3] = 0.f;
            pr0 = pr0 * sd0 + (acc0 + xt.x) * pi0;   // new psc_rise
            pr1 = pr1 * sd1 + (acc1 + xt.y) * pi1;
            pr2 = pr2 * sd2 + (acc2 + xt.z) * pi2;
            pr3 = pr3 * sd3 + (acc3 + xt.w) * pi3;
            out[(size_t)t * N + n] = nz;             // in the barrier shadow
            zz = nz;
        }

        if (!lastT) {
            float4 xtn = own ? x_ext4[(size_t)(t + 1) * N + n] : zf;

            // ---- WAIT (release likely already set) + stage mask(t) ----
            if (tid == 0 && !i_released) {
                unsigned* rl = barr + (size_t)t * 160 + 144;
                while (!__hip_atomic_load(rl, __ATOMIC_RELAXED,
                                          __HIP_MEMORY_SCOPE_AGENT))
                    __builtin_amdgcn_s_sleep(1);
            }
            __syncthreads();                      // S3: released; zeroes done

            const unsigned long long* gm = (t & 1) ? mB : mA;
            unsigned long long m0 = 0ull, m1 = 0ull;
            if (tid < nmask)
                m0 = __hip_atomic_load(&gm[tid], __ATOMIC_RELAXED,
                                       __HIP_MEMORY_SCOPE_AGENT);
            if (tid + BS < nmask)
                m1 = __hip_atomic_load(&gm[tid + BS], __ATOMIC_RELAXED,
                                       __HIP_MEMORY_SCOPE_AGENT);
            if (tid < nmask) smask[tid] = m0;
            if (tid + BS < nmask) smask[tid + BS] = m1;
            anyspk = __syncthreads_or((m0 | m1) != 0ull ? 1 : 0);   // S4
            xt = xtn;
        }
    }
}

// ---------------- launch ----------------
extern "C" void kernel_launch(void* const* d_in, const int* in_sizes, int n_in,
                              void* d_out, int out_size, void* d_ws, size_t ws_size,
                              hipStream_t stream) {
    const float* w_rec = (const float*)d_in[0];
    const float* x_ext = (const float*)d_in[1];
    const float* v0    = (const float*)d_in[2];
    const float* v_th  = (const float*)d_in[3];
    const float* v_rst = (const float*)d_in[4];
    const float* t_rf  = (const float*)d_in[5];
    const float* decay = (const float*)d_in[6];
    const float* curf  = (const float*)d_in[7];
    const float* e_l   = (const float*)d_in[8];
    const float* aamps = (const float*)d_in[9];
    const float* adec  = (const float*)d_in[10];
    const float* syn_d = (const float*)d_in[11];
    const float* psc_i = (const float*)d_in[12];
    const int*   pre   = (const int*)d_in[13];
    const int*   post  = (const int*)d_in[14];
    const int*   rc    = (const int*)d_in[15];

    const int E = in_sizes[0];
    const int N = in_sizes[2];            // B == 1
    const int T = in_sizes[1] / (N * RR);
    const int nmask = (N + 63) / 64;
    const int NBK = (N + BKN - 1) / BKN;  // buckets == sim blocks (196)
    const int CH  = (E + NCH - 1) / NCH;
    const int nbar = 160 * T;             // per step: 8 group + top + release lines
    const int EP  = E + 4 * NBK;          // padded edge capacity

    // -------- workspace layout --------
    char* ws = (char*)d_ws;
    unsigned* epack  = (unsigned*)ws;                     ws += (size_t)EP * 4;
    float*    ew     = (float*)ws;                        ws += (size_t)EP * 4;
    unsigned long long* maskA = (unsigned long long*)ws;  ws += (size_t)nmask * 8;
    unsigned long long* maskB = (unsigned long long*)ws;  ws += (size_t)nmask * 8;
    int* ghist       = (int*)ws;                          ws += (size_t)NBK * NCH * 4;
    int* rtot        = (int*)ws;                          ws += (size_t)NBK * 4;
    int* ptot        = (int*)ws;                          ws += (size_t)NBK * 4;
    int* bstart      = (int*)ws;                          ws += (size_t)(NBK + 1) * 4;
    unsigned* barr   = (unsigned*)ws;                     /* +nbar*4 */

    // -------- setup (4 dispatches, contention-free) --------
    count_kernel<<<NCH, 256, 0, stream>>>(post, ghist, maskA, maskB, barr,
                                          E, CH, NBK, nmask, nbar);
    scanA_kernel<<<NBK, NCH, 0, stream>>>(ghist, rtot, ptot);
    scanB_kernel<<<1, 256, 0, stream>>>(rtot, ptot, bstart, epack, ew, NBK);
    fill_kernel<<<NCH, 256, 0, stream>>>(pre, post, rc, w_rec, ghist, bstart,
                                         epack, ew, E, CH, NBK);

    // -------- persistent sim: 196 blocks x 1024, 1 block/CU ----------------
    const size_t smbytes = (size_t)nmask * 8 + (size_t)BKN * RR * 4;  // ~20.5 KB
    sim_kernel<<<NBK, BS, smbytes, stream>>>(
        (const float4*)x_ext, v0, v_th, v_rst, t_rf, decay, curf, e_l,
        (const float2*)aamps, (const float2*)adec, syn_d, psc_i,
        (const uint4*)epack, (const float4*)ew, bstart, maskA, maskB, barr,
        (float*)d_out, N, nmask, T);
}